// Round 1
// baseline (576.171 us; speedup 1.0000x reference)
//
#include <hip/hip_runtime.h>

// ---------------------------------------------------------------------------
// LINKX-ish GNN forward:
//   deg/dinv -> agg (D^-1/2 A D^-1/2 x, self loops) ->
//   h1x = relu(x@W1x+b1x); h1a = relu(agg@W1a+b1a)
//   out = relu(h1x@Wxp + h1a@Wap + bp) @ Wcls + bcls
// where Wxp = W2x@Wc[0:128], Wap = W2a@Wc[128:256],
//       bp = b2x@Wc_top + b2a@Wc_bot + bc   (precomputed on device per call)
// ---------------------------------------------------------------------------

__global__ void k_zero(float* __restrict__ p, int n) {
  int i = blockIdx.x * 256 + threadIdx.x;
  if (i < n) p[i] = 0.f;
}

// Detect whether edge_index is int64 (all odd int32 slots of first 64 elems zero)
__global__ void k_detect(const int* __restrict__ ei, int* __restrict__ flag) {
  int t = threadIdx.x;  // 64 threads
  int v = ei[2 * t + 1];
  unsigned long long b = __ballot(v == 0);
  if (t == 0) *flag = (b == ~0ULL) ? 1 : 0;
}

__device__ __forceinline__ int edge_at(const void* ei, long pos, int is64) {
  if (is64) return (int)((const long long*)ei)[pos];
  return ((const int*)ei)[pos];
}

__global__ void k_deg(const void* __restrict__ ei, int E, float* __restrict__ deg,
                      const int* __restrict__ flag) {
  int e = blockIdx.x * 256 + threadIdx.x;
  int is64 = *flag;
  if (e < E) {
    int r = edge_at(ei, e, is64);
    atomicAdd(&deg[r], 1.0f);
  }
}

__global__ void k_dinv(float* __restrict__ d, int N) {
  int i = blockIdx.x * 256 + threadIdx.x;
  if (i < N) d[i] = rsqrtf(d[i] + 1.0f);  // +1 = self loop
}

// agg[i] = x[i] * dinv[i]^2   (self-loop term)
__global__ void k_agg_self(const float* __restrict__ x, const float* __restrict__ dinv,
                           float* __restrict__ agg, long total) {
  long idx = (long)blockIdx.x * 256 + threadIdx.x;
  if (idx < total) {
    int i = (int)(idx >> 6);
    float d = dinv[i];
    agg[idx] = x[idx] * d * d;
  }
}

// one wave (64 lanes) per edge: lane f handles feature f
__global__ void k_agg_edges(const void* __restrict__ ei, const float* __restrict__ dinv,
                            const float* __restrict__ x, float* __restrict__ agg,
                            int E, const int* __restrict__ flag) {
  long t = (long)blockIdx.x * 256 + threadIdx.x;
  int e = (int)(t >> 6);
  int f = threadIdx.x & 63;
  int is64 = *flag;
  if (e < E) {
    int r = edge_at(ei, e, is64);
    int c = edge_at(ei, (long)E + e, is64);
    float w = dinv[r] * dinv[c];
    atomicAdd(&agg[(long)r * 64 + f], x[(long)c * 64 + f] * w);
  }
}

// Wxp = W2x @ Wc_top ; Wap = W2a @ Wc_bot ; bp = b2x@Wc_top + b2a@Wc_bot + bc
__global__ void k_wprod(const float* __restrict__ W2x, const float* __restrict__ W2a,
                        const float* __restrict__ Wc, const float* __restrict__ b2x,
                        const float* __restrict__ b2a, const float* __restrict__ bc,
                        float* __restrict__ Wxp, float* __restrict__ Wap,
                        float* __restrict__ bp) {
  int b = blockIdx.x, t = threadIdx.x;
  if (b < 128) {
    int j = t & 127;
    bool isX = (t < 128);
    const float* wrow = isX ? (W2x + b * 128) : (W2a + b * 128);
    const float* wc = isX ? Wc : (Wc + 128 * 128);
    float s = 0.f;
    for (int m = 0; m < 128; ++m) s = fmaf(wrow[m], wc[m * 128 + j], s);
    (isX ? Wxp : Wap)[b * 128 + j] = s;
  } else if (t < 128) {
    float s = bc[t];
    for (int m = 0; m < 128; ++m)
      s += b2x[m] * Wc[m * 128 + t] + b2a[m] * Wc[(128 + m) * 128 + t];
    bp[t] = s;
  }
}

// C[N][128] = relu(A[N][64] @ W[64][128] + b), BM=128, 256 thr, 8x8 per thread
__global__ __launch_bounds__(256) void k_gemm1(
    const float* __restrict__ A, const float* __restrict__ W,
    const float* __restrict__ bias, float* __restrict__ C, int N) {
  __shared__ float Ast[64][132];  // transposed tile: Ast[k][m], pad keeps f4 align
  __shared__ float Ws[64][132];
  const int tid = threadIdx.x;
  const int row0 = blockIdx.x * 128;
#pragma unroll
  for (int r = 0; r < 8; ++r) {
    int f4 = tid + r * 256;       // 0..2047 (128 rows x 16 f4)
    int m = f4 >> 4;
    int k4 = (f4 & 15) << 2;
    int gr = row0 + m;
    float4 v = make_float4(0.f, 0.f, 0.f, 0.f);
    if (gr < N) v = *(const float4*)(A + (long)gr * 64 + k4);
    Ast[k4 + 0][m] = v.x; Ast[k4 + 1][m] = v.y;
    Ast[k4 + 2][m] = v.z; Ast[k4 + 3][m] = v.w;
  }
#pragma unroll
  for (int r = 0; r < 8; ++r) {
    int f4 = tid + r * 256;       // 0..2047 (64 rows x 32 f4)
    int k = f4 >> 5;
    int j4 = (f4 & 31) << 2;
    *(float4*)&Ws[k][j4] = *(const float4*)(W + k * 128 + j4);
  }
  __syncthreads();
  const int ty = tid >> 4;        // rows ty*8..
  const int tx = tid & 15;        // cols tx*4.. and 64+tx*4..
  float acc[8][8] = {};
#pragma unroll 4
  for (int k = 0; k < 64; ++k) {
    float4 a0 = *(const float4*)&Ast[k][ty * 8];
    float4 a1 = *(const float4*)&Ast[k][ty * 8 + 4];
    float4 w0 = *(const float4*)&Ws[k][tx * 4];
    float4 w1 = *(const float4*)&Ws[k][64 + tx * 4];
    float a[8] = {a0.x, a0.y, a0.z, a0.w, a1.x, a1.y, a1.z, a1.w};
    float w[8] = {w0.x, w0.y, w0.z, w0.w, w1.x, w1.y, w1.z, w1.w};
#pragma unroll
    for (int i = 0; i < 8; ++i)
#pragma unroll
      for (int j = 0; j < 8; ++j) acc[i][j] = fmaf(a[i], w[j], acc[i][j]);
  }
  float4 b0 = *(const float4*)(bias + tx * 4);
  float4 b1 = *(const float4*)(bias + 64 + tx * 4);
  float bv[8] = {b0.x, b0.y, b0.z, b0.w, b1.x, b1.y, b1.z, b1.w};
#pragma unroll
  for (int i = 0; i < 8; ++i) {
    int gr = row0 + ty * 8 + i;
    if (gr < N) {
      float4 o0, o1;
      o0.x = fmaxf(acc[i][0] + bv[0], 0.f); o0.y = fmaxf(acc[i][1] + bv[1], 0.f);
      o0.z = fmaxf(acc[i][2] + bv[2], 0.f); o0.w = fmaxf(acc[i][3] + bv[3], 0.f);
      o1.x = fmaxf(acc[i][4] + bv[4], 0.f); o1.y = fmaxf(acc[i][5] + bv[5], 0.f);
      o1.z = fmaxf(acc[i][6] + bv[6], 0.f); o1.w = fmaxf(acc[i][7] + bv[7], 0.f);
      *(float4*)(C + (long)gr * 128 + tx * 4) = o0;
      *(float4*)(C + (long)gr * 128 + 64 + tx * 4) = o1;
    }
  }
}

// out[N][64] = relu(A1@Wxp + A2@Wap + bp) @ Wcls + bcls, BM=64 rows per block
__global__ __launch_bounds__(256) void k_gemm23(
    const float* __restrict__ A1, const float* __restrict__ A2,
    const float* __restrict__ Wxp, const float* __restrict__ Wap,
    const float* __restrict__ bp, const float* __restrict__ Wcls,
    const float* __restrict__ bcls, float* __restrict__ C, int N) {
  __shared__ float smem[17152];               // 68.6KB, unioned across phases
  float (*Ast)[68] = (float(*)[68])smem;      // [64][68] transposed A chunk
  float (*Ws)[132] = (float(*)[132])(smem + 64 * 68);  // [64][132]
  const int tid = threadIdx.x;
  const int row0 = blockIdx.x * 64;
  const int ty = tid >> 5;   // rows ty*8..
  const int tx = tid & 31;   // cols tx*4..
  float acc[8][4] = {};
  for (int pass = 0; pass < 4; ++pass) {
    const float* A = (pass < 2) ? A1 : A2;
    const float* W = (pass < 2) ? Wxp : Wap;
    const int kc = (pass & 1) * 64;
    __syncthreads();
#pragma unroll
    for (int r = 0; r < 4; ++r) {
      int f4 = tid + r * 256;   // 0..1023 (64 rows x 16 f4)
      int m = f4 >> 4;
      int k4 = (f4 & 15) << 2;
      int gr = row0 + m;
      float4 v = make_float4(0.f, 0.f, 0.f, 0.f);
      if (gr < N) v = *(const float4*)(A + (long)gr * 128 + kc + k4);
      Ast[k4 + 0][m] = v.x; Ast[k4 + 1][m] = v.y;
      Ast[k4 + 2][m] = v.z; Ast[k4 + 3][m] = v.w;
    }
#pragma unroll
    for (int r = 0; r < 8; ++r) {
      int f4 = tid + r * 256;   // 0..2047 (64 rows x 32 f4)
      int k = f4 >> 5;
      int j4 = (f4 & 31) << 2;
      *(float4*)&Ws[k][j4] = *(const float4*)(W + (kc + k) * 128 + j4);
    }
    __syncthreads();
#pragma unroll 4
    for (int k = 0; k < 64; ++k) {
      float4 a0 = *(const float4*)&Ast[k][ty * 8];
      float4 a1 = *(const float4*)&Ast[k][ty * 8 + 4];
      float4 wv = *(const float4*)&Ws[k][tx * 4];
      float a[8] = {a0.x, a0.y, a0.z, a0.w, a1.x, a1.y, a1.z, a1.w};
      float w[4] = {wv.x, wv.y, wv.z, wv.w};
#pragma unroll
      for (int i = 0; i < 8; ++i)
#pragma unroll
        for (int j = 0; j < 4; ++j) acc[i][j] = fmaf(a[i], w[j], acc[i][j]);
    }
  }
  // h = relu(acc + bp)
  float4 bv = *(const float4*)(bp + tx * 4);
  float h[8][4];
#pragma unroll
  for (int i = 0; i < 8; ++i) {
    h[i][0] = fmaxf(acc[i][0] + bv.x, 0.f);
    h[i][1] = fmaxf(acc[i][1] + bv.y, 0.f);
    h[i][2] = fmaxf(acc[i][2] + bv.z, 0.f);
    h[i][3] = fmaxf(acc[i][3] + bv.w, 0.f);
  }
  __syncthreads();  // all phase-1 LDS reads done before repurposing smem
  float (*Hs)[132] = (float(*)[132])smem;               // [64][132]
  float (*Wcs)[68] = (float(*)[68])(smem + 64 * 132);   // [128][68]
#pragma unroll
  for (int i = 0; i < 8; ++i)
    *(float4*)&Hs[ty * 8 + i][tx * 4] = make_float4(h[i][0], h[i][1], h[i][2], h[i][3]);
#pragma unroll
  for (int r = 0; r < 8; ++r) {
    int f4 = tid + r * 256;   // 0..2047 (128 rows x 16 f4)
    int k = f4 >> 4;
    int j4 = (f4 & 15) << 2;
    *(float4*)&Wcs[k][j4] = *(const float4*)(Wcls + k * 64 + j4);
  }
  __syncthreads();
  const int ty2 = tid >> 4;  // rows ty2*4..
  const int tx2 = tid & 15;  // cols tx2*4..
  float o[4][4] = {};
#pragma unroll 4
  for (int k = 0; k < 128; ++k) {
    float4 wv = *(const float4*)&Wcs[k][tx2 * 4];
    float av[4];
#pragma unroll
    for (int i = 0; i < 4; ++i) av[i] = Hs[ty2 * 4 + i][k];
#pragma unroll
    for (int i = 0; i < 4; ++i) {
      o[i][0] = fmaf(av[i], wv.x, o[i][0]);
      o[i][1] = fmaf(av[i], wv.y, o[i][1]);
      o[i][2] = fmaf(av[i], wv.z, o[i][2]);
      o[i][3] = fmaf(av[i], wv.w, o[i][3]);
    }
  }
  float4 bc2 = *(const float4*)(bcls + tx2 * 4);
#pragma unroll
  for (int i = 0; i < 4; ++i) {
    int gr = row0 + ty2 * 4 + i;
    if (gr < N) {
      float4 ov;
      ov.x = o[i][0] + bc2.x; ov.y = o[i][1] + bc2.y;
      ov.z = o[i][2] + bc2.z; ov.w = o[i][3] + bc2.w;
      *(float4*)(C + (long)gr * 64 + tx2 * 4) = ov;
    }
  }
}

extern "C" void kernel_launch(void* const* d_in, const int* in_sizes, int n_in,
                              void* d_out, int out_size, void* d_ws, size_t ws_size,
                              hipStream_t stream) {
  const float* x    = (const float*)d_in[0];
  const void*  ei   = d_in[1];
  const float* W1x  = (const float*)d_in[2];
  const float* b1x  = (const float*)d_in[3];
  const float* W2x  = (const float*)d_in[4];
  const float* b2x  = (const float*)d_in[5];
  const float* W1a  = (const float*)d_in[6];
  const float* b1a  = (const float*)d_in[7];
  const float* W2a  = (const float*)d_in[8];
  const float* b2a  = (const float*)d_in[9];
  const float* Wc   = (const float*)d_in[10];
  const float* bc   = (const float*)d_in[11];
  const float* Wcls = (const float*)d_in[12];
  const float* bcls = (const float*)d_in[13];
  const int N = in_sizes[0] / 64;
  const int E = in_sizes[1] / 2;

  float* ws   = (float*)d_ws;
  float* deg  = ws;                                   // N (becomes dinv in place)
  int*   flag = (int*)(ws + ((N + 255) & ~255));      // 1
  float* agg  = ws + ((N + 255) & ~255) + 256;        // N*64
  float* h1x  = agg + (long)N * 64;                   // N*128
  float* h1a  = h1x + (long)N * 128;                  // N*128
  float* Wxp  = h1a + (long)N * 128;                  // 16384
  float* Wap  = Wxp + 16384;                          // 16384
  float* bp   = Wap + 16384;                          // 128
  float* out  = (float*)d_out;

  k_detect<<<1, 64, 0, stream>>>((const int*)ei, flag);
  k_zero<<<(N + 255) / 256, 256, 0, stream>>>(deg, N);
  k_deg<<<(E + 255) / 256, 256, 0, stream>>>(ei, E, deg, flag);
  k_dinv<<<(N + 255) / 256, 256, 0, stream>>>(deg, N);
  k_agg_self<<<(int)(((long)N * 64 + 255) / 256), 256, 0, stream>>>(x, deg, agg, (long)N * 64);
  k_agg_edges<<<(E + 3) / 4, 256, 0, stream>>>(ei, deg, x, agg, E, flag);
  k_wprod<<<129, 256, 0, stream>>>(W2x, W2a, Wc, b2x, b2a, bc, Wxp, Wap, bp);
  k_gemm1<<<(N + 127) / 128, 256, 0, stream>>>(x, W1x, b1x, h1x, N);
  k_gemm1<<<(N + 127) / 128, 256, 0, stream>>>(agg, W1a, b1a, h1a, N);
  k_gemm23<<<(N + 63) / 64, 256, 0, stream>>>(h1x, h1a, Wxp, Wap, bp, Wcls, bcls, out, N);
}

// Round 2
// 382.676 us; speedup vs baseline: 1.5056x; 1.5056x over previous
//
#include <hip/hip_runtime.h>
#include <stdint.h>

// ---------------------------------------------------------------------------
// LINKX-ish GNN forward:
//   CSR build -> agg = D^-1/2 (A+I) D^-1/2 x  (atomic-free row aggregation)
//   h1x = relu(x@W1x+b1x); h1a = relu(agg@W1a+b1a)
//   out = relu(h1x@Wxp + h1a@Wap + bp) @ Wcls + bcls
// where Wxp = W2x@Wc[0:128], Wap = W2a@Wc[128:256],
//       bp = b2x@Wc_top + b2a@Wc_bot + bc   (precomputed on device per call)
// ---------------------------------------------------------------------------

__global__ void k_zero(int* __restrict__ p, int n) {
  int i = blockIdx.x * 256 + threadIdx.x;
  if (i < n) p[i] = 0;
}

// Detect whether edge_index is int64 (all odd int32 slots of first 64 elems zero)
__global__ void k_detect(const int* __restrict__ ei, int* __restrict__ flag) {
  int t = threadIdx.x;  // 64 threads
  int v = ei[2 * t + 1];
  unsigned long long b = __ballot(v == 0);
  if (t == 0) *flag = (b == ~0ULL) ? 1 : 0;
}

__device__ __forceinline__ int edge_at(const void* ei, long pos, int is64) {
  if (is64) return (int)((const long long*)ei)[pos];
  return ((const int*)ei)[pos];
}

__global__ void k_hist(const void* __restrict__ ei, int E, int* __restrict__ cnt,
                       const int* __restrict__ flag) {
  int e = blockIdx.x * 256 + threadIdx.x;
  int is64 = *flag;
  if (e < E) atomicAdd(&cnt[edge_at(ei, e, is64)], 1);
}

// inclusive scan per 256-block
__global__ void k_scan1(const int* __restrict__ cnt, int* __restrict__ incl,
                        int* __restrict__ bsum, int N) {
  __shared__ int s[256];
  int t = threadIdx.x, i = blockIdx.x * 256 + t;
  int v = (i < N) ? cnt[i] : 0;
  s[t] = v;
  __syncthreads();
#pragma unroll
  for (int off = 1; off < 256; off <<= 1) {
    int u = (t >= off) ? s[t - off] : 0;
    __syncthreads();
    s[t] += u;
    __syncthreads();
  }
  if (i < N) incl[i] = s[t];
  if (t == 255) bsum[blockIdx.x] = s[t];
}

// exclusive scan of block sums in place (nb <= 1024), single block
__global__ void k_scan2(int* __restrict__ bsum, int nb) {
  __shared__ int s[1024];
  int t = threadIdx.x;
  int v = (t < nb) ? bsum[t] : 0;
  s[t] = v;
  __syncthreads();
#pragma unroll
  for (int off = 1; off < 1024; off <<= 1) {
    int u = (t >= off) ? s[t - off] : 0;
    __syncthreads();
    s[t] += u;
    __syncthreads();
  }
  if (t < nb) bsum[t] = s[t] - v;  // exclusive
}

__global__ void k_scan3(const int* __restrict__ cnt, const int* __restrict__ incl,
                        const int* __restrict__ bsum, int* __restrict__ rowptr,
                        int* __restrict__ cursor, float* __restrict__ dinv,
                        int N, int E) {
  int i = blockIdx.x * 256 + threadIdx.x;
  if (i < N) {
    int ex = incl[i] - cnt[i] + bsum[i >> 8];
    rowptr[i] = ex;
    cursor[i] = ex;
    dinv[i] = rsqrtf((float)cnt[i] + 1.0f);  // +1 = self loop
    if (i == N - 1) rowptr[N] = E;
  }
}

// scatter edges into CSR slots; pack (col, weight) as int2 for one 8B load later
__global__ void k_scatter(const void* __restrict__ ei, int E,
                          const float* __restrict__ dinv, int* __restrict__ cursor,
                          int2* __restrict__ colwt, const int* __restrict__ flag) {
  int e = blockIdx.x * 256 + threadIdx.x;
  int is64 = *flag;
  if (e < E) {
    int r = edge_at(ei, e, is64);
    int c = edge_at(ei, (long)E + e, is64);
    int pos = atomicAdd(&cursor[r], 1);
    int2 v;
    v.x = c;
    v.y = __float_as_int(dinv[r] * dinv[c]);
    colwt[pos] = v;
  }
}

// one wave per row; lane f = feature f; self loop folded in; unroll-by-4
__global__ __launch_bounds__(256) void k_aggregate(
    const int* __restrict__ rowptr, const int2* __restrict__ colwt,
    const float* __restrict__ x, const float* __restrict__ dinv,
    float* __restrict__ agg, int N) {
  int r = (blockIdx.x * 256 + threadIdx.x) >> 6;
  int f = threadIdx.x & 63;
  if (r >= N) return;
  int j = rowptr[r], end = rowptr[r + 1];
  float dr = dinv[r];
  float acc = x[(long)r * 64 + f] * dr * dr;
  for (; j + 4 <= end; j += 4) {
    int2 e0 = colwt[j], e1 = colwt[j + 1], e2 = colwt[j + 2], e3 = colwt[j + 3];
    float x0 = x[(long)e0.x * 64 + f];
    float x1 = x[(long)e1.x * 64 + f];
    float x2 = x[(long)e2.x * 64 + f];
    float x3 = x[(long)e3.x * 64 + f];
    acc = fmaf(x0, __int_as_float(e0.y), acc);
    acc = fmaf(x1, __int_as_float(e1.y), acc);
    acc = fmaf(x2, __int_as_float(e2.y), acc);
    acc = fmaf(x3, __int_as_float(e3.y), acc);
  }
  for (; j < end; ++j) {
    int2 e0 = colwt[j];
    acc = fmaf(x[(long)e0.x * 64 + f], __int_as_float(e0.y), acc);
  }
  agg[(long)r * 64 + f] = acc;
}

// Wxp = W2x @ Wc_top ; Wap = W2a @ Wc_bot ; bp = b2x@Wc_top + b2a@Wc_bot + bc
__global__ void k_wprod(const float* __restrict__ W2x, const float* __restrict__ W2a,
                        const float* __restrict__ Wc, const float* __restrict__ b2x,
                        const float* __restrict__ b2a, const float* __restrict__ bc,
                        float* __restrict__ Wxp, float* __restrict__ Wap,
                        float* __restrict__ bp) {
  int b = blockIdx.x, t = threadIdx.x;
  if (b < 128) {
    int j = t & 127;
    bool isX = (t < 128);
    const float* wrow = isX ? (W2x + b * 128) : (W2a + b * 128);
    const float* wc = isX ? Wc : (Wc + 128 * 128);
    float s = 0.f;
    for (int m = 0; m < 128; ++m) s = fmaf(wrow[m], wc[m * 128 + j], s);
    (isX ? Wxp : Wap)[b * 128 + j] = s;
  } else if (t < 128) {
    float s = bc[t];
    for (int m = 0; m < 128; ++m)
      s += b2x[m] * Wc[m * 128 + t] + b2a[m] * Wc[(128 + m) * 128 + t];
    bp[t] = s;
  }
}

// C[N][128] = relu(A[N][64] @ W[64][128] + b), BM=128, 256 thr, 8x8 per thread
__global__ __launch_bounds__(256) void k_gemm1(
    const float* __restrict__ A, const float* __restrict__ W,
    const float* __restrict__ bias, float* __restrict__ C, int N) {
  __shared__ float Ast[64][132];  // transposed tile: Ast[k][m], pad keeps f4 align
  __shared__ float Ws[64][132];
  const int tid = threadIdx.x;
  const int row0 = blockIdx.x * 128;
#pragma unroll
  for (int r = 0; r < 8; ++r) {
    int f4 = tid + r * 256;       // 0..2047 (128 rows x 16 f4)
    int m = f4 >> 4;
    int k4 = (f4 & 15) << 2;
    int gr = row0 + m;
    float4 v = make_float4(0.f, 0.f, 0.f, 0.f);
    if (gr < N) v = *(const float4*)(A + (long)gr * 64 + k4);
    Ast[k4 + 0][m] = v.x; Ast[k4 + 1][m] = v.y;
    Ast[k4 + 2][m] = v.z; Ast[k4 + 3][m] = v.w;
  }
#pragma unroll
  for (int r = 0; r < 8; ++r) {
    int f4 = tid + r * 256;       // 0..2047 (64 rows x 32 f4)
    int k = f4 >> 5;
    int j4 = (f4 & 31) << 2;
    *(float4*)&Ws[k][j4] = *(const float4*)(W + k * 128 + j4);
  }
  __syncthreads();
  const int ty = tid >> 4;        // rows ty*8..
  const int tx = tid & 15;        // cols tx*4.. and 64+tx*4..
  float acc[8][8] = {};
#pragma unroll 4
  for (int k = 0; k < 64; ++k) {
    float4 a0 = *(const float4*)&Ast[k][ty * 8];
    float4 a1 = *(const float4*)&Ast[k][ty * 8 + 4];
    float4 w0 = *(const float4*)&Ws[k][tx * 4];
    float4 w1 = *(const float4*)&Ws[k][64 + tx * 4];
    float a[8] = {a0.x, a0.y, a0.z, a0.w, a1.x, a1.y, a1.z, a1.w};
    float w[8] = {w0.x, w0.y, w0.z, w0.w, w1.x, w1.y, w1.z, w1.w};
#pragma unroll
    for (int i = 0; i < 8; ++i)
#pragma unroll
      for (int j = 0; j < 8; ++j) acc[i][j] = fmaf(a[i], w[j], acc[i][j]);
  }
  float4 b0 = *(const float4*)(bias + tx * 4);
  float4 b1 = *(const float4*)(bias + 64 + tx * 4);
  float bv[8] = {b0.x, b0.y, b0.z, b0.w, b1.x, b1.y, b1.z, b1.w};
#pragma unroll
  for (int i = 0; i < 8; ++i) {
    int gr = row0 + ty * 8 + i;
    if (gr < N) {
      float4 o0, o1;
      o0.x = fmaxf(acc[i][0] + bv[0], 0.f); o0.y = fmaxf(acc[i][1] + bv[1], 0.f);
      o0.z = fmaxf(acc[i][2] + bv[2], 0.f); o0.w = fmaxf(acc[i][3] + bv[3], 0.f);
      o1.x = fmaxf(acc[i][4] + bv[4], 0.f); o1.y = fmaxf(acc[i][5] + bv[5], 0.f);
      o1.z = fmaxf(acc[i][6] + bv[6], 0.f); o1.w = fmaxf(acc[i][7] + bv[7], 0.f);
      *(float4*)(C + (long)gr * 128 + tx * 4) = o0;
      *(float4*)(C + (long)gr * 128 + 64 + tx * 4) = o1;
    }
  }
}

// out[N][64] = relu(A1@Wxp + A2@Wap + bp) @ Wcls + bcls, BM=64 rows per block
__global__ __launch_bounds__(256) void k_gemm23(
    const float* __restrict__ A1, const float* __restrict__ A2,
    const float* __restrict__ Wxp, const float* __restrict__ Wap,
    const float* __restrict__ bp, const float* __restrict__ Wcls,
    const float* __restrict__ bcls, float* __restrict__ C, int N) {
  __shared__ float smem[17152];               // 68.6KB, unioned across phases
  float (*Ast)[68] = (float(*)[68])smem;      // [64][68] transposed A chunk
  float (*Ws)[132] = (float(*)[132])(smem + 64 * 68);  // [64][132]
  const int tid = threadIdx.x;
  const int row0 = blockIdx.x * 64;
  const int ty = tid >> 5;   // rows ty*8..
  const int tx = tid & 31;   // cols tx*4..
  float acc[8][4] = {};
  for (int pass = 0; pass < 4; ++pass) {
    const float* A = (pass < 2) ? A1 : A2;
    const float* W = (pass < 2) ? Wxp : Wap;
    const int kc = (pass & 1) * 64;
    __syncthreads();
#pragma unroll
    for (int r = 0; r < 4; ++r) {
      int f4 = tid + r * 256;   // 0..1023 (64 rows x 16 f4)
      int m = f4 >> 4;
      int k4 = (f4 & 15) << 2;
      int gr = row0 + m;
      float4 v = make_float4(0.f, 0.f, 0.f, 0.f);
      if (gr < N) v = *(const float4*)(A + (long)gr * 128 + kc + k4);
      Ast[k4 + 0][m] = v.x; Ast[k4 + 1][m] = v.y;
      Ast[k4 + 2][m] = v.z; Ast[k4 + 3][m] = v.w;
    }
#pragma unroll
    for (int r = 0; r < 8; ++r) {
      int f4 = tid + r * 256;   // 0..2047 (64 rows x 32 f4)
      int k = f4 >> 5;
      int j4 = (f4 & 31) << 2;
      *(float4*)&Ws[k][j4] = *(const float4*)(W + (kc + k) * 128 + j4);
    }
    __syncthreads();
#pragma unroll 4
    for (int k = 0; k < 64; ++k) {
      float4 a0 = *(const float4*)&Ast[k][ty * 8];
      float4 a1 = *(const float4*)&Ast[k][ty * 8 + 4];
      float4 wv = *(const float4*)&Ws[k][tx * 4];
      float a[8] = {a0.x, a0.y, a0.z, a0.w, a1.x, a1.y, a1.z, a1.w};
      float w[4] = {wv.x, wv.y, wv.z, wv.w};
#pragma unroll
      for (int i = 0; i < 8; ++i)
#pragma unroll
        for (int j = 0; j < 4; ++j) acc[i][j] = fmaf(a[i], w[j], acc[i][j]);
    }
  }
  // h = relu(acc + bp)
  float4 bv = *(const float4*)(bp + tx * 4);
  float h[8][4];
#pragma unroll
  for (int i = 0; i < 8; ++i) {
    h[i][0] = fmaxf(acc[i][0] + bv.x, 0.f);
    h[i][1] = fmaxf(acc[i][1] + bv.y, 0.f);
    h[i][2] = fmaxf(acc[i][2] + bv.z, 0.f);
    h[i][3] = fmaxf(acc[i][3] + bv.w, 0.f);
  }
  __syncthreads();  // all phase-1 LDS reads done before repurposing smem
  float (*Hs)[132] = (float(*)[132])smem;               // [64][132]
  float (*Wcs)[68] = (float(*)[68])(smem + 64 * 132);   // [128][68]
#pragma unroll
  for (int i = 0; i < 8; ++i)
    *(float4*)&Hs[ty * 8 + i][tx * 4] = make_float4(h[i][0], h[i][1], h[i][2], h[i][3]);
#pragma unroll
  for (int r = 0; r < 8; ++r) {
    int f4 = tid + r * 256;   // 0..2047 (128 rows x 16 f4)
    int k = f4 >> 4;
    int j4 = (f4 & 15) << 2;
    *(float4*)&Wcs[k][j4] = *(const float4*)(Wcls + k * 64 + j4);
  }
  __syncthreads();
  const int ty2 = tid >> 4;  // rows ty2*4..
  const int tx2 = tid & 15;  // cols tx2*4..
  float o[4][4] = {};
#pragma unroll 4
  for (int k = 0; k < 128; ++k) {
    float4 wv = *(const float4*)&Wcs[k][tx2 * 4];
    float av[4];
#pragma unroll
    for (int i = 0; i < 4; ++i) av[i] = Hs[ty2 * 4 + i][k];
#pragma unroll
    for (int i = 0; i < 4; ++i) {
      o[i][0] = fmaf(av[i], wv.x, o[i][0]);
      o[i][1] = fmaf(av[i], wv.y, o[i][1]);
      o[i][2] = fmaf(av[i], wv.z, o[i][2]);
      o[i][3] = fmaf(av[i], wv.w, o[i][3]);
    }
  }
  float4 bc2 = *(const float4*)(bcls + tx2 * 4);
#pragma unroll
  for (int i = 0; i < 4; ++i) {
    int gr = row0 + ty2 * 4 + i;
    if (gr < N) {
      float4 ov;
      ov.x = o[i][0] + bc2.x; ov.y = o[i][1] + bc2.y;
      ov.z = o[i][2] + bc2.z; ov.w = o[i][3] + bc2.w;
      *(float4*)(C + (long)gr * 64 + tx2 * 4) = ov;
    }
  }
}

extern "C" void kernel_launch(void* const* d_in, const int* in_sizes, int n_in,
                              void* d_out, int out_size, void* d_ws, size_t ws_size,
                              hipStream_t stream) {
  const float* x    = (const float*)d_in[0];
  const void*  ei   = d_in[1];
  const float* W1x  = (const float*)d_in[2];
  const float* b1x  = (const float*)d_in[3];
  const float* W2x  = (const float*)d_in[4];
  const float* b2x  = (const float*)d_in[5];
  const float* W1a  = (const float*)d_in[6];
  const float* b1a  = (const float*)d_in[7];
  const float* W2a  = (const float*)d_in[8];
  const float* b2a  = (const float*)d_in[9];
  const float* Wc   = (const float*)d_in[10];
  const float* bc   = (const float*)d_in[11];
  const float* Wcls = (const float*)d_in[12];
  const float* bcls = (const float*)d_in[13];
  const int N = in_sizes[0] / 64;
  const int E = in_sizes[1] / 2;

  float* ws   = (float*)d_ws;
  long nAlign = (N + 255) & ~255L;
  float* dinv = ws;                                   // N
  int*   flag = (int*)(ws + nAlign);                  // 1
  float* agg  = ws + nAlign + 256;                    // N*64
  float* h1x  = agg + (long)N * 64;                   // N*128
  float* h1a  = h1x + (long)N * 128;                  // N*128
  float* Wxp  = h1a + (long)N * 128;                  // 16384
  float* Wap  = Wxp + 16384;                          // 16384
  float* bp   = Wap + 16384;                          // 128
  float* out  = (float*)d_out;

  // graph arrays overlay the h1x region (dead until k_gemm1 writes it, which
  // runs after k_aggregate finishes reading these)
  int*  cnt    = (int*)h1x;                           // N
  int*  incl   = cnt + N;                             // N
  int*  bsum   = incl + N;                            // 1024
  int*  rowptr = bsum + 1024;                         // N+1
  int*  cursor = rowptr + N + 1;                      // N
  int2* colwt  = (int2*)(((uintptr_t)(cursor + N) + 15) & ~(uintptr_t)15);  // E

  const int nb = (N + 255) / 256;
  k_detect<<<1, 64, 0, stream>>>((const int*)ei, flag);
  k_zero<<<nb, 256, 0, stream>>>(cnt, N);
  k_hist<<<(E + 255) / 256, 256, 0, stream>>>(ei, E, cnt, flag);
  k_scan1<<<nb, 256, 0, stream>>>(cnt, incl, bsum, N);
  k_scan2<<<1, 1024, 0, stream>>>(bsum, nb);
  k_scan3<<<nb, 256, 0, stream>>>(cnt, incl, bsum, rowptr, cursor, dinv, N, E);
  k_scatter<<<(E + 255) / 256, 256, 0, stream>>>(ei, E, dinv, cursor, colwt, flag);
  k_aggregate<<<(N * 64 + 255) / 256, 256, 0, stream>>>(rowptr, colwt, x, dinv, agg, N);
  k_wprod<<<129, 256, 0, stream>>>(W2x, W2a, Wc, b2x, b2a, bc, Wxp, Wap, bp);
  k_gemm1<<<(N + 127) / 128, 256, 0, stream>>>(x, W1x, b1x, h1x, N);
  k_gemm1<<<(N + 127) / 128, 256, 0, stream>>>(agg, W1a, b1a, h1a, N);
  k_gemm23<<<(N + 63) / 64, 256, 0, stream>>>(h1x, h1a, Wxp, Wap, bp, Wcls, bcls, out, N);
}

// Round 3
// 244.037 us; speedup vs baseline: 2.3610x; 1.5681x over previous
//
#include <hip/hip_runtime.h>
#include <stdint.h>

typedef unsigned short u16;
typedef __attribute__((ext_vector_type(8))) short frag_ab;   // 8 bf16
typedef __attribute__((ext_vector_type(4))) float f32x4;

__device__ __forceinline__ u16 f2b(float f) {
  unsigned u = __float_as_uint(f);
  return (u16)((u + 0x7fffu + ((u >> 16) & 1u)) >> 16);
}
__device__ __forceinline__ float b2f(u16 u) {
  return __uint_as_float(((unsigned)u) << 16);
}

// ---------------------------------------------------------------------------

__global__ void k_zero(int* __restrict__ p, int n) {
  int i = blockIdx.x * 256 + threadIdx.x;
  if (i < n) p[i] = 0;
}

__global__ void k_detect(const int* __restrict__ ei, int* __restrict__ flag) {
  int t = threadIdx.x;  // 64 threads
  int v = ei[2 * t + 1];
  unsigned long long b = __ballot(v == 0);
  if (t == 0) *flag = (b == ~0ULL) ? 1 : 0;
}

__device__ __forceinline__ int edge_at(const void* ei, long pos, int is64) {
  if (is64) return (int)((const long long*)ei)[pos];
  return ((const int*)ei)[pos];
}

__global__ void k_hist(const void* __restrict__ ei, int E, int* __restrict__ cnt,
                       const int* __restrict__ flag) {
  int e = blockIdx.x * 256 + threadIdx.x;
  int is64 = *flag;
  if (e < E) atomicAdd(&cnt[edge_at(ei, e, is64)], 1);
}

__global__ void k_scan1(const int* __restrict__ cnt, int* __restrict__ incl,
                        int* __restrict__ bsum, int N) {
  __shared__ int s[256];
  int t = threadIdx.x, i = blockIdx.x * 256 + t;
  int v = (i < N) ? cnt[i] : 0;
  s[t] = v;
  __syncthreads();
  for (int off = 1; off < 256; off <<= 1) {
    int u = (t >= off) ? s[t - off] : 0;
    __syncthreads();
    s[t] += u;
    __syncthreads();
  }
  if (i < N) incl[i] = s[t];
  if (t == 255) bsum[blockIdx.x] = s[t];
}

__global__ void k_scan2(int* __restrict__ bsum, int nb) {
  __shared__ int s[1024];
  int t = threadIdx.x;
  int v = (t < nb) ? bsum[t] : 0;
  s[t] = v;
  __syncthreads();
  for (int off = 1; off < 1024; off <<= 1) {
    int u = (t >= off) ? s[t - off] : 0;
    __syncthreads();
    s[t] += u;
    __syncthreads();
  }
  if (t < nb) bsum[t] = s[t] - v;  // exclusive
}

__global__ void k_scan3(const int* __restrict__ cnt, const int* __restrict__ incl,
                        const int* __restrict__ bsum, int* __restrict__ rowptr,
                        int* __restrict__ cursor, float* __restrict__ dinv,
                        int N, int E) {
  int i = blockIdx.x * 256 + threadIdx.x;
  if (i < N) {
    int ex = incl[i] - cnt[i] + bsum[i >> 8];
    rowptr[i] = ex;
    cursor[i] = ex;
    dinv[i] = rsqrtf((float)cnt[i] + 1.0f);  // +1 = self loop
    if (i == N - 1) rowptr[N] = E;
  }
}

__global__ void k_scatter(const void* __restrict__ ei, int E,
                          const float* __restrict__ dinv, int* __restrict__ cursor,
                          int2* __restrict__ colwt, const int* __restrict__ flag) {
  int e = blockIdx.x * 256 + threadIdx.x;
  int is64 = *flag;
  if (e < E) {
    int r = edge_at(ei, e, is64);
    int c = edge_at(ei, (long)E + e, is64);
    int pos = atomicAdd(&cursor[r], 1);
    int2 v;
    v.x = c;
    v.y = __float_as_int(dinv[r] * dinv[c]);
    colwt[pos] = v;
  }
}

// fp32 -> bf16, 8 elems/thread
__global__ void k_cvt(const float* __restrict__ src, u16* __restrict__ dst, long n) {
  long i = ((long)blockIdx.x * 256 + threadIdx.x) * 8;
  if (i + 8 <= n) {
    float4 v0 = *(const float4*)(src + i);
    float4 v1 = *(const float4*)(src + i + 4);
    frag_ab o;
    o[0] = (short)f2b(v0.x); o[1] = (short)f2b(v0.y);
    o[2] = (short)f2b(v0.z); o[3] = (short)f2b(v0.w);
    o[4] = (short)f2b(v1.x); o[5] = (short)f2b(v1.y);
    o[6] = (short)f2b(v1.z); o[7] = (short)f2b(v1.w);
    *(frag_ab*)(dst + i) = o;
  }
}

// one wave per row; lane f = feature f (bf16 gather); self loop folded in
__global__ __launch_bounds__(256) void k_aggregate(
    const int* __restrict__ rowptr, const int2* __restrict__ colwt,
    const u16* __restrict__ xb, const float* __restrict__ dinv,
    u16* __restrict__ aggb, int N) {
  int r = (blockIdx.x * 256 + threadIdx.x) >> 6;
  int f = threadIdx.x & 63;
  if (r >= N) return;
  int j = rowptr[r], end = rowptr[r + 1];
  float dr = dinv[r];
  float acc = b2f(xb[(long)r * 64 + f]) * dr * dr;
  for (; j + 4 <= end; j += 4) {
    int2 e0 = colwt[j], e1 = colwt[j + 1], e2 = colwt[j + 2], e3 = colwt[j + 3];
    float x0 = b2f(xb[(long)e0.x * 64 + f]);
    float x1 = b2f(xb[(long)e1.x * 64 + f]);
    float x2 = b2f(xb[(long)e2.x * 64 + f]);
    float x3 = b2f(xb[(long)e3.x * 64 + f]);
    acc = fmaf(x0, __int_as_float(e0.y), acc);
    acc = fmaf(x1, __int_as_float(e1.y), acc);
    acc = fmaf(x2, __int_as_float(e2.y), acc);
    acc = fmaf(x3, __int_as_float(e3.y), acc);
  }
  for (; j < end; ++j) {
    int2 e0 = colwt[j];
    acc = fmaf(b2f(xb[(long)e0.x * 64 + f]), __int_as_float(e0.y), acc);
  }
  aggb[(long)r * 64 + f] = f2b(acc);
}

// Wxp = W2x @ Wc_top ; Wap = W2a @ Wc_bot ; bp = b2x@Wc_top + b2a@Wc_bot + bc
__global__ void k_wprod(const float* __restrict__ W2x, const float* __restrict__ W2a,
                        const float* __restrict__ Wc, const float* __restrict__ b2x,
                        const float* __restrict__ b2a, const float* __restrict__ bc,
                        float* __restrict__ Wxp, float* __restrict__ Wap,
                        float* __restrict__ bp) {
  int b = blockIdx.x, t = threadIdx.x;
  if (b < 128) {
    int j = t & 127;
    bool isX = (t < 128);
    const float* wrow = isX ? (W2x + b * 128) : (W2a + b * 128);
    const float* wc = isX ? Wc : (Wc + 128 * 128);
    float s = 0.f;
    for (int m = 0; m < 128; ++m) s = fmaf(wrow[m], wc[m * 128 + j], s);
    (isX ? Wxp : Wap)[b * 128 + j] = s;
  } else if (t < 128) {
    float s = bc[t];
    for (int m = 0; m < 128; ++m)
      s += b2x[m] * Wc[m * 128 + t] + b2a[m] * Wc[(128 + m) * 128 + t];
    bp[t] = s;
  }
}

// pack W[K][Nc] fp32 row-major into bf16 B-fragment-linear order:
// dst[((nb*KB+kb)*64 + lane)*8 + b] = bf16(W[kb*32 + (lane>>4)*8 + b][nb*16 + (lane&15)])
__global__ void k_pack(const float* __restrict__ W, u16* __restrict__ dst,
                       int K, int Nc) {
  int i = blockIdx.x * 256 + threadIdx.x;
  if (i >= K * Nc) return;
  int b = i & 7, l = (i >> 3) & 63, f = i >> 9;
  int KB = K >> 5;
  int kb = f % KB, nb = f / KB;
  int k = kb * 32 + (l >> 4) * 8 + b;
  int n = nb * 16 + (l & 15);
  dst[i] = f2b(W[k * Nc + n]);
}

// ---------------------------------------------------------------------------
// Fused MLP: per 64-row block (4 waves, 16 rows/wave, wave-local pipeline):
//   H1[:,0:128]=relu(x@W1x+b1x); H1[:,128:256]=relu(agg@W1a+b1a)   (LDS, swz)
//   H2=relu(H1@[Wxp;Wap]+bp)                                        (LDS, swz)
//   out=H2@Wcls+bcls
// B-frags come fragment-linear from global (L2-hot); A-frags layer1 from global.
// ---------------------------------------------------------------------------
__global__ __launch_bounds__(256) void k_mlp(
    const u16* __restrict__ xb, const u16* __restrict__ aggb,
    const u16* __restrict__ W1xf, const u16* __restrict__ W1af,
    const float* __restrict__ b1x, const float* __restrict__ b1a,
    const u16* __restrict__ Wxpf, const u16* __restrict__ Wapf,
    const float* __restrict__ bp,
    const u16* __restrict__ Wclsf, const float* __restrict__ bcls,
    float* __restrict__ out, int N) {
  __shared__ u16 H1[4][16 * 256];   // 32KB, per-wave [16 rows][256 feats], swizzled
  __shared__ u16 H2[4][16 * 128];   // 16KB
  const int w = threadIdx.x >> 6;
  const int lane = threadIdx.x & 63;
  const int m0 = blockIdx.x * 64 + w * 16;
  const int lm = lane & 15;
  const int lq = lane >> 4;
  u16* h1 = H1[w];
  u16* h2 = H2[w];

  // ---- phase 1
  for (int br = 0; br < 2; ++br) {
    const u16* A = br ? aggb : xb;
    const u16* Wf = br ? W1af : W1xf;
    const float* bias = br ? b1a : b1x;
    const u16* ap = A + (long)(m0 + lm) * 64 + lq * 8;
    frag_ab a0 = *(const frag_ab*)(ap);
    frag_ab a1 = *(const frag_ab*)(ap + 32);
#pragma unroll
    for (int nb = 0; nb < 8; ++nb) {
      frag_ab b0 = *(const frag_ab*)(Wf + (size_t)((nb * 2 + 0) * 64 + lane) * 8);
      frag_ab b1v = *(const frag_ab*)(Wf + (size_t)((nb * 2 + 1) * 64 + lane) * 8);
      f32x4 acc = {0.f, 0.f, 0.f, 0.f};
      acc = __builtin_amdgcn_mfma_f32_16x16x32_bf16(a0, b0, acc, 0, 0, 0);
      acc = __builtin_amdgcn_mfma_f32_16x16x32_bf16(a1, b1v, acc, 0, 0, 0);
      int col = nb * 16 + lm;
      float bv = bias[col];
#pragma unroll
      for (int r = 0; r < 4; ++r) {
        int row = lq * 4 + r;
        h1[(row * 256 + br * 128 + col) ^ ((row & 7) << 3)] =
            f2b(fmaxf(acc[r] + bv, 0.f));
      }
    }
  }
  __syncthreads();

  // ---- phase 2: H2 = relu(H1 @ [Wxp;Wap] + bp), K=256
  frag_ab hfr[8];
#pragma unroll
  for (int kb = 0; kb < 8; ++kb)
    hfr[kb] = *(const frag_ab*)&h1[(lm * 256 + kb * 32 + lq * 8) ^ ((lm & 7) << 3)];
#pragma unroll
  for (int nb = 0; nb < 8; ++nb) {
    f32x4 acc = {0.f, 0.f, 0.f, 0.f};
#pragma unroll
    for (int kb = 0; kb < 8; ++kb) {
      const u16* Wf2 = (kb < 4) ? Wxpf : Wapf;
      frag_ab b = *(const frag_ab*)(Wf2 + (size_t)((nb * 4 + (kb & 3)) * 64 + lane) * 8);
      acc = __builtin_amdgcn_mfma_f32_16x16x32_bf16(hfr[kb], b, acc, 0, 0, 0);
    }
    int col = nb * 16 + lm;
    float bv = bp[col];
#pragma unroll
    for (int r = 0; r < 4; ++r) {
      int row = lq * 4 + r;
      h2[(row * 128 + col) ^ ((row & 7) << 3)] = f2b(fmaxf(acc[r] + bv, 0.f));
    }
  }
  __syncthreads();

  // ---- phase 3: out = H2 @ Wcls + bcls, K=128, Nc=64
  frag_ab h3[4];
#pragma unroll
  for (int kb = 0; kb < 4; ++kb)
    h3[kb] = *(const frag_ab*)&h2[(lm * 128 + kb * 32 + lq * 8) ^ ((lm & 7) << 3)];
#pragma unroll
  for (int nb = 0; nb < 4; ++nb) {
    f32x4 acc = {0.f, 0.f, 0.f, 0.f};
#pragma unroll
    for (int kb = 0; kb < 4; ++kb) {
      frag_ab b = *(const frag_ab*)(Wclsf + (size_t)((nb * 4 + kb) * 64 + lane) * 8);
      acc = __builtin_amdgcn_mfma_f32_16x16x32_bf16(h3[kb], b, acc, 0, 0, 0);
    }
    int col = nb * 16 + lm;
    float bv = bcls[col];
#pragma unroll
    for (int r = 0; r < 4; ++r) {
      int grow = m0 + lq * 4 + r;
      if (grow < N) out[(long)grow * 64 + col] = acc[r] + bv;
    }
  }
}

extern "C" void kernel_launch(void* const* d_in, const int* in_sizes, int n_in,
                              void* d_out, int out_size, void* d_ws, size_t ws_size,
                              hipStream_t stream) {
  const float* x    = (const float*)d_in[0];
  const void*  ei   = d_in[1];
  const float* W1x  = (const float*)d_in[2];
  const float* b1x  = (const float*)d_in[3];
  const float* W2x  = (const float*)d_in[4];
  const float* b2x  = (const float*)d_in[5];
  const float* W1a  = (const float*)d_in[6];
  const float* b1a  = (const float*)d_in[7];
  const float* W2a  = (const float*)d_in[8];
  const float* b2a  = (const float*)d_in[9];
  const float* Wc   = (const float*)d_in[10];
  const float* bc   = (const float*)d_in[11];
  const float* Wcls = (const float*)d_in[12];
  const float* bcls = (const float*)d_in[13];
  const int N = in_sizes[0] / 64;
  const int E = in_sizes[1] / 2;

  float* ws = (float*)d_ws;
  long nAlign = (N + 255) & ~255L;
  float* dinv = ws;                                    // N
  int*   flag = (int*)(ws + nAlign);                   // 1
  u16*   xb   = (u16*)(ws + nAlign + 256);             // N*64 bf16
  u16*   aggb = xb + (long)N * 64;                     // N*64 bf16
  float* Wxp  = (float*)(aggb + (long)N * 64);         // 16384
  float* Wap  = Wxp + 16384;                           // 16384
  float* bp   = Wap + 16384;                           // 128
  u16*   W1xf = (u16*)(bp + 128);                      // 8192
  u16*   W1af = W1xf + 8192;                           // 8192
  u16*   Wxpf = W1af + 8192;                           // 16384
  u16*   Wapf = Wxpf + 16384;                          // 16384
  u16*   Wclsf = Wapf + 16384;                         // 8192
  int*   cnt    = (int*)(Wclsf + 8192);                // N
  int*   incl   = cnt + N;                             // N
  int*   bsum   = incl + N;                            // 1024
  int*   rowptr = bsum + 1024;                         // N+1
  int*   cursor = rowptr + N + 1;                      // N
  int2*  colwt  = (int2*)(((uintptr_t)(cursor + N) + 15) & ~(uintptr_t)15);  // E
  float* out = (float*)d_out;

  const int nb = (N + 255) / 256;
  k_detect<<<1, 64, 0, stream>>>((const int*)ei, flag);
  k_zero<<<nb, 256, 0, stream>>>(cnt, N);
  k_hist<<<(E + 255) / 256, 256, 0, stream>>>(ei, E, cnt, flag);
  k_scan1<<<nb, 256, 0, stream>>>(cnt, incl, bsum, N);
  k_scan2<<<1, 1024, 0, stream>>>(bsum, nb);
  k_scan3<<<nb, 256, 0, stream>>>(cnt, incl, bsum, rowptr, cursor, dinv, N, E);
  k_scatter<<<(E + 255) / 256, 256, 0, stream>>>(ei, E, dinv, cursor, colwt, flag);
  k_cvt<<<(int)(((long)N * 64 / 8 + 255) / 256), 256, 0, stream>>>(x, xb, (long)N * 64);
  k_aggregate<<<(N * 64 + 255) / 256, 256, 0, stream>>>(rowptr, colwt, xb, dinv, aggb, N);
  k_wprod<<<129, 256, 0, stream>>>(W2x, W2a, Wc, b2x, b2a, bc, Wxp, Wap, bp);
  k_pack<<<32, 256, 0, stream>>>(W1x, W1xf, 64, 128);
  k_pack<<<32, 256, 0, stream>>>(W1a, W1af, 64, 128);
  k_pack<<<64, 256, 0, stream>>>(Wxp, Wxpf, 128, 128);
  k_pack<<<64, 256, 0, stream>>>(Wap, Wapf, 128, 128);
  k_pack<<<32, 256, 0, stream>>>(Wcls, Wclsf, 128, 64);
  k_mlp<<<(N + 63) / 64, 256, 0, stream>>>(xb, aggb, W1xf, W1af, b1x, b1a,
                                           Wxpf, Wapf, bp, Wclsf, bcls, out, N);
}